// Round 11
// baseline (897.660 us; speedup 1.0000x reference)
//
#include <hip/hip_runtime.h>
#include <hip/hip_bf16.h>

#define NN 100000
#define NE 1600000
#define SCAN_BLOCKS 98   // ceil(100000/1024)

typedef short short8 __attribute__((ext_vector_type(8)));
typedef float floatx4 __attribute__((ext_vector_type(4)));
typedef int   intx4   __attribute__((ext_vector_type(4)));

__device__ __forceinline__ float silu_f(float x){ return x / (1.0f + __expf(-x)); }

__device__ __forceinline__ unsigned short f2bf(float x) {
    __hip_bfloat16 h = __float2bfloat16(x);   // hardware RNE cvt
    unsigned short u; __builtin_memcpy(&u, &h, 2); return u;
}
__device__ __forceinline__ float bf2f(unsigned short u) {
    return __uint_as_float((unsigned)u << 16);
}

// ---------- LDS dot (round-2..5 proven: measured SQ_LDS_BANK_CONFLICT == 0) ----------
__device__ __forceinline__ float dot64(const float* vec, const float* wrow) {
    float ax = 0.f, ay = 0.f, az = 0.f, aw = 0.f;
#pragma unroll
    for (int k = 0; k < 64; k += 4) {
        float4 w = *(const float4*)(wrow + k);
        float4 v = *(const float4*)(vec + k);
        ax = fmaf(v.x, w.x, ax); ay = fmaf(v.y, w.y, ay);
        az = fmaf(v.z, w.z, az); aw = fmaf(v.w, w.w, aw);
    }
    return (ax + ay) + (az + aw);
}
__device__ __forceinline__ void load_wT(const float* __restrict__ w, float* s, int t) {
    for (int i = t; i < 4096; i += 256) { int k = i >> 6, j = i & 63; s[j * 68 + k] = w[i]; }
}

// tvec[j] = b_t[j] + silu(1) * sum_{i=16..31} w_t[i][j]
__global__ void tvec_kernel(const float* __restrict__ w_t, const float* __restrict__ b_t,
                            float* __restrict__ tvec) {
    int j = threadIdx.x;
    const float s1 = 0.7310585786300049f;
    float acc = b_t[j];
#pragma unroll
    for (int i = 16; i < 32; ++i) acc = fmaf(s1, w_t[i * 64 + j], acc);
    tvec[j] = acc;
}

__global__ __launch_bounds__(256) void node_init_kernel(
    const float* __restrict__ cond,
    const float* __restrict__ w1, const float* __restrict__ b1,
    const float* __restrict__ w2, const float* __restrict__ b2,
    const float* __restrict__ tvec,
    float* __restrict__ h, float* __restrict__ agg)   // agg==nullptr on fast path
{
    __shared__ float s_w1[6 * 64];
    __shared__ float s_w2t[64 * 68];
    __shared__ float s_b1[64], s_b2[64];
    __shared__ float s_hid[4][64];
    int t = threadIdx.x;
    for (int i = t; i < 384; i += 256) s_w1[i] = w1[64 + i]; // rows 1..6 (row 0 hits zero column)
    load_wT(w2, s_w2t, t);
    if (t < 64) { s_b1[t] = b1[t]; s_b2[t] = b2[t] + tvec[t]; }
    __syncthreads();
    int lane = t & 63, grp = t >> 6;
    const int groups = (NN + 3) >> 2;
    for (int g = blockIdx.x; g < groups; g += gridDim.x) {
        int n = (g << 2) + grp;
        if (n < NN) {
            float acc = s_b1[lane];
#pragma unroll
            for (int i = 0; i < 6; ++i) acc = fmaf(cond[n * 6 + i], s_w1[i * 64 + lane], acc);
            s_hid[grp][lane] = silu_f(acc);
            float o = s_b2[lane] + dot64(s_hid[grp], s_w2t + lane * 68);
            size_t off = (size_t)n * 64 + lane;
            h[off] = o;
            if (agg) agg[off] = 0.f;
        }
    }
}

// ---------- CSR build ----------
__global__ __launch_bounds__(256) void zero_kernel(int* __restrict__ p, int n) {
    int i = blockIdx.x * 256 + threadIdx.x;
    if (i < n) p[i] = 0;
}
// histogram AND per-edge rank (rank = old count at dst)
__global__ __launch_bounds__(256) void hist_rank_kernel(const int* __restrict__ dst,
                                                        int* __restrict__ cnt,
                                                        int* __restrict__ rank) {
    int e = blockIdx.x * 256 + threadIdx.x;
    if (e < NE) rank[e] = atomicAdd(&cnt[dst[e]], 1);
}
__global__ __launch_bounds__(256) void scan1_kernel(const int* __restrict__ cnt,
                                                    int* __restrict__ offs, int* __restrict__ bsum) {
    __shared__ int s_w[4];
    int t = threadIdx.x;
    int base = blockIdx.x * 1024 + t * 4;
    int v0 = (base + 0 < NN) ? cnt[base + 0] : 0;
    int v1 = (base + 1 < NN) ? cnt[base + 1] : 0;
    int v2 = (base + 2 < NN) ? cnt[base + 2] : 0;
    int v3 = (base + 3 < NN) ? cnt[base + 3] : 0;
    int tsum = v0 + v1 + v2 + v3;
    int lane = t & 63, w = t >> 6;
    int x = tsum;
#pragma unroll
    for (int d = 1; d < 64; d <<= 1) { int y = __shfl_up(x, d, 64); if (lane >= d) x += y; }
    if (lane == 63) s_w[w] = x;
    __syncthreads();
    if (t == 0) {
        int a = 0;
#pragma unroll
        for (int i = 0; i < 4; ++i) { int b = s_w[i]; s_w[i] = a; a += b; }
        bsum[blockIdx.x] = a;
    }
    __syncthreads();
    int excl = x - tsum + s_w[w];
    if (base + 0 < NN) offs[base + 0] = excl;
    if (base + 1 < NN) offs[base + 1] = excl + v0;
    if (base + 2 < NN) offs[base + 2] = excl + v0 + v1;
    if (base + 3 < NN) offs[base + 3] = excl + v0 + v1 + v2;
}
__global__ void scan2_kernel(const int* __restrict__ bsum, int* __restrict__ bscan, int nb) {
    __shared__ int s_w[2];
    int t = threadIdx.x;
    int v = (t < nb) ? bsum[t] : 0;
    int lane = t & 63, w = t >> 6;
    int x = v;
#pragma unroll
    for (int d = 1; d < 64; d <<= 1) { int y = __shfl_up(x, d, 64); if (lane >= d) x += y; }
    if (lane == 63) s_w[w] = x;
    __syncthreads();
    int add = (w == 1) ? s_w[0] : 0;
    if (t < nb) bscan[t] = x - v + add;
}
__global__ __launch_bounds__(256) void scan3_kernel(int* __restrict__ offs,
                                                    const int* __restrict__ bscan) {
    int i = blockIdx.x * 256 + threadIdx.x;
    if (i < NN) offs[i] = offs[i] + bscan[i >> 10];
    if (i == 0) offs[NN] = NE;
}
// atomic-free scatter: pos = offs[dst] + rank  (offs is read-only, L2-replicated)
__global__ __launch_bounds__(256) void scatter_pack_kernel(const int* __restrict__ dst,
                                                           const int* __restrict__ src,
                                                           const float* __restrict__ ea,
                                                           const int* __restrict__ offs,
                                                           const int* __restrict__ rank,
                                                           intx4* __restrict__ pack) {
    int e = blockIdx.x * 256 + threadIdx.x;
    if (e >= NE) return;
    float2 a = *(const float2*)(ea + (size_t)e * 2);
    int pos = offs[dst[e]] + rank[e];
    intx4 p = { src[e], __float_as_int(a.x), __float_as_int(a.y), 0 };
    pack[pos] = p;
}
// zero the 16-entry pack pad (reads past NE must be finite)
__global__ void pad_pack_kernel(intx4* __restrict__ pack) {
    intx4 z = {0, 0, 0, 0};
    pack[NE + threadIdx.x] = z;
}

// ---------- FUSED aggregation: recompute edge MLP via MFMA inline, no ef buffer ----------
// Per wave: one node. Per 16-CSR-slot batch:
//   A-frag (16x16x32 bf16): lane(er,kg) holds hid[edge er][k=c*32+kg*8+j] (layer-1 in VALU)
//   B-frag: w2 retiled, tile tt -> phys col 4*er+tt (proven since round 6)
//   C/D: lane(er,kg) holds ef[row=kg*4+q][phys cols 4er..4er+3] in e0..e3[q]  (fp32!)
//   Then per row q-step: shfl src, gather h row (dwordx4), relu(h+ef+b2) accumulate.
__global__ __launch_bounds__(256, 2) void agg_fused_kernel(
    const float* __restrict__ hin, float* __restrict__ u,
    const int* __restrict__ offs, const intx4* __restrict__ pack,
    const float* __restrict__ w1, const float* __restrict__ b1,
    const float* __restrict__ w2, const float* __restrict__ b2)
{
    int t = threadIdx.x, lane = t & 63, wv = t >> 6;
    int er = lane & 15, kg = lane >> 4;
    // layer-1 weights for this lane's 16 k values (loop-invariant VGPRs)
    float w1x[2][8], w1y[2][8], b1v[2][8];
#pragma unroll
    for (int c = 0; c < 2; ++c)
#pragma unroll
        for (int j = 0; j < 8; ++j) {
            int k = c * 32 + kg * 8 + j;
            w1x[c][j] = w1[k];
            w1y[c][j] = w1[64 + k];
            b1v[c][j] = b1[k];
        }
    short8 bfrag[2][4];
#pragma unroll
    for (int c = 0; c < 2; ++c)
#pragma unroll
        for (int tt = 0; tt < 4; ++tt)
#pragma unroll
            for (int j = 0; j < 8; ++j) {
                int k = c * 32 + kg * 8 + j;
                bfrag[c][tt][j] = (short)f2bf(w2[k * 64 + 4 * er + tt]);
            }
    float4 b2v = *(const float4*)(b2 + 4 * er);

    int n = blockIdx.x * 4 + wv;
    if (n >= NN) return;
    int i0 = offs[n], i1 = offs[n + 1];
    float ax0 = 0.f, ax1 = 0.f, ax2 = 0.f, ax3 = 0.f;   // partial col sums (this lane's kg rows)
    for (int ib = i0; ib < i1; ib += 16) {
        int m = i1 - ib; if (m > 16) m = 16;
        intx4 p = pack[ib + er];                  // all 4 kg groups same addr -> broadcast
        float eax = __int_as_float(p.y), eay = __int_as_float(p.z);
        short8 afrag[2];
#pragma unroll
        for (int c = 0; c < 2; ++c)
#pragma unroll
            for (int j = 0; j < 8; ++j) {
                float hid = silu_f(fmaf(eax, w1x[c][j], fmaf(eay, w1y[c][j], b1v[c][j])));
                afrag[c][j] = (short)f2bf(hid);
            }
        floatx4 e0 = {0,0,0,0}, e1 = {0,0,0,0}, e2 = {0,0,0,0}, e3 = {0,0,0,0};
        e0 = __builtin_amdgcn_mfma_f32_16x16x32_bf16(afrag[0], bfrag[0][0], e0, 0, 0, 0);
        e0 = __builtin_amdgcn_mfma_f32_16x16x32_bf16(afrag[1], bfrag[1][0], e0, 0, 0, 0);
        e1 = __builtin_amdgcn_mfma_f32_16x16x32_bf16(afrag[0], bfrag[0][1], e1, 0, 0, 0);
        e1 = __builtin_amdgcn_mfma_f32_16x16x32_bf16(afrag[1], bfrag[1][1], e1, 0, 0, 0);
        e2 = __builtin_amdgcn_mfma_f32_16x16x32_bf16(afrag[0], bfrag[0][2], e2, 0, 0, 0);
        e2 = __builtin_amdgcn_mfma_f32_16x16x32_bf16(afrag[1], bfrag[1][2], e2, 0, 0, 0);
        e3 = __builtin_amdgcn_mfma_f32_16x16x32_bf16(afrag[0], bfrag[0][3], e3, 0, 0, 0);
        e3 = __builtin_amdgcn_mfma_f32_16x16x32_bf16(afrag[1], bfrag[1][3], e3, 0, 0, 0);
#pragma unroll
        for (int q = 0; q < 4; ++q) {
            int r = kg * 4 + q;
            int sr = __shfl(p.x, r, 64);          // src of edge row r (lane r holds it)
            if (r < m) {                           // uniform within each 16-lane kg group
                float4 hv = *(const float4*)(hin + (size_t)sr * 64 + 4 * er);
                ax0 += fmaxf(hv.x + e0[q] + b2v.x, 0.f);
                ax1 += fmaxf(hv.y + e1[q] + b2v.y, 0.f);
                ax2 += fmaxf(hv.z + e2[q] + b2v.z, 0.f);
                ax3 += fmaxf(hv.w + e3[q] + b2v.w, 0.f);
            }
        }
    }
    // reduce across the 4 kg groups (lane^16, lane^32 keep er fixed)
#pragma unroll
    for (int d = 16; d <= 32; d <<= 1) {
        ax0 += __shfl_xor(ax0, d, 64);
        ax1 += __shfl_xor(ax1, d, 64);
        ax2 += __shfl_xor(ax2, d, 64);
        ax3 += __shfl_xor(ax3, d, 64);
    }
    if (kg == 0) {
        float4 self = *(const float4*)(hin + (size_t)n * 64 + 4 * er);
        float4 o;
        o.x = self.x + ax0; o.y = self.y + ax1;
        o.z = self.z + ax2; o.w = self.w + ax3;
        *(float4*)(u + (size_t)n * 64 + 4 * er) = o;
    }
}

// ---------- node MLP via MFMA, 3-term bf16 split (~fp32 precision), weights in B-frags ----------
__global__ __launch_bounds__(256) void node_mlp_mfma_kernel(
    const float* __restrict__ u, float* __restrict__ h,
    const float* __restrict__ wa, const float* __restrict__ ba,
    const float* __restrict__ wb, const float* __restrict__ bb)
{
    __shared__ float s_hid[4][16 * 72];
    int t = threadIdx.x, lane = t & 63, wv = t >> 6;
    int er = lane & 15, kg = lane >> 4;
    short8 waH[2][4], waL[2][4], wbH[2][4], wbL[2][4];
#pragma unroll
    for (int c = 0; c < 2; ++c)
#pragma unroll
        for (int tt = 0; tt < 4; ++tt)
#pragma unroll
            for (int j = 0; j < 8; ++j) {
                int k = c * 32 + kg * 8 + j;
                float vA = wa[k * 64 + 4 * er + tt];
                unsigned short hA = f2bf(vA);
                waH[c][tt][j] = (short)hA;
                waL[c][tt][j] = (short)f2bf(vA - bf2f(hA));
                float vB = wb[k * 64 + 4 * er + tt];
                unsigned short hB = f2bf(vB);
                wbH[c][tt][j] = (short)hB;
                wbL[c][tt][j] = (short)f2bf(vB - bf2f(hB));
            }
    float4 bav = *(const float4*)(ba + 4 * er);
    float4 bbv = *(const float4*)(bb + 4 * er);
    float* hid = s_hid[wv];

    const int ntile = NN / 16;  // 6250
    for (int tile = blockIdx.x * 4 + wv; tile < ntile; tile += gridDim.x * 4) {
        int i0 = tile * 16;
        short8 aH[2], aL[2];
#pragma unroll
        for (int c = 0; c < 2; ++c) {
            const float* up = u + (size_t)(i0 + er) * 64 + c * 32 + kg * 8;
            float4 u0 = *(const float4*)(up);
            float4 u1 = *(const float4*)(up + 4);
            float uv[8] = {u0.x, u0.y, u0.z, u0.w, u1.x, u1.y, u1.z, u1.w};
#pragma unroll
            for (int j = 0; j < 8; ++j) {
                unsigned short hi = f2bf(uv[j]);
                aH[c][j] = (short)hi;
                aL[c][j] = (short)f2bf(uv[j] - bf2f(hi));
            }
        }
        floatx4 acc[4] = {{0,0,0,0},{0,0,0,0},{0,0,0,0},{0,0,0,0}};
#pragma unroll
        for (int tt = 0; tt < 4; ++tt)
#pragma unroll
            for (int c = 0; c < 2; ++c) {
                acc[tt] = __builtin_amdgcn_mfma_f32_16x16x32_bf16(aH[c], waH[c][tt], acc[tt], 0, 0, 0);
                acc[tt] = __builtin_amdgcn_mfma_f32_16x16x32_bf16(aL[c], waH[c][tt], acc[tt], 0, 0, 0);
                acc[tt] = __builtin_amdgcn_mfma_f32_16x16x32_bf16(aH[c], waL[c][tt], acc[tt], 0, 0, 0);
            }
#pragma unroll
        for (int q = 0; q < 4; ++q) {
            float4 hv;
            hv.x = silu_f(acc[0][q] + bav.x);
            hv.y = silu_f(acc[1][q] + bav.y);
            hv.z = silu_f(acc[2][q] + bav.z);
            hv.w = silu_f(acc[3][q] + bav.w);
            *(float4*)(hid + (kg * 4 + q) * 72 + 4 * er) = hv;
        }
        short8 cH[2], cL[2];
#pragma unroll
        for (int c = 0; c < 2; ++c) {
            const float* hp = hid + er * 72 + c * 32 + kg * 8;
            float4 h0 = *(const float4*)(hp);
            float4 h1 = *(const float4*)(hp + 4);
            float hv[8] = {h0.x, h0.y, h0.z, h0.w, h1.x, h1.y, h1.z, h1.w};
#pragma unroll
            for (int j = 0; j < 8; ++j) {
                unsigned short hi = f2bf(hv[j]);
                cH[c][j] = (short)hi;
                cL[c][j] = (short)f2bf(hv[j] - bf2f(hi));
            }
        }
        floatx4 acc2[4] = {{0,0,0,0},{0,0,0,0},{0,0,0,0},{0,0,0,0}};
#pragma unroll
        for (int tt = 0; tt < 4; ++tt)
#pragma unroll
            for (int c = 0; c < 2; ++c) {
                acc2[tt] = __builtin_amdgcn_mfma_f32_16x16x32_bf16(cH[c], wbH[c][tt], acc2[tt], 0, 0, 0);
                acc2[tt] = __builtin_amdgcn_mfma_f32_16x16x32_bf16(cL[c], wbH[c][tt], acc2[tt], 0, 0, 0);
                acc2[tt] = __builtin_amdgcn_mfma_f32_16x16x32_bf16(cH[c], wbL[c][tt], acc2[tt], 0, 0, 0);
            }
#pragma unroll
        for (int q = 0; q < 4; ++q) {
            float4 ov;
            ov.x = silu_f(acc2[0][q] + bbv.x);
            ov.y = silu_f(acc2[1][q] + bbv.y);
            ov.z = silu_f(acc2[2][q] + bbv.z);
            ov.w = silu_f(acc2[3][q] + bbv.w);
            *(float4*)(h + (size_t)(i0 + kg * 4 + q) * 64 + 4 * er) = ov;
        }
    }
}

// ---------- fallback path (round-2 proven) ----------
__global__ __launch_bounds__(256, 3) void edge_feat_fallback_kernel(
    const float* __restrict__ ea,
    const float* __restrict__ w1, const float* __restrict__ b1,
    const float* __restrict__ w2, const float* __restrict__ b2,
    __hip_bfloat16* __restrict__ ef)
{
    __shared__ float s_w1[128], s_b1[64], s_b2[64];
    __shared__ float s_hid[4][64];
    int t = threadIdx.x;
    if (t < 128) s_w1[t] = w1[t];
    if (t < 64) { s_b1[t] = b1[t]; s_b2[t] = b2[t]; }
    int lane = t & 63, grp = t >> 6;
    __syncthreads();
    const int groups = NE >> 2;
    for (int g = blockIdx.x; g < groups; g += gridDim.x) {
        int e = (g << 2) + grp;
        float2 a = *(const float2*)(ea + (size_t)e * 2);
        float acc = fmaf(a.x, s_w1[lane], fmaf(a.y, s_w1[64 + lane], s_b1[lane]));
        s_hid[grp][lane] = silu_f(acc);
        float o = s_b2[lane];
#pragma unroll
        for (int k = 0; k < 64; k += 4) {
            float4 v = *(const float4*)&s_hid[grp][k];
            o = fmaf(v.x, w2[(k+0)*64+lane], o);
            o = fmaf(v.y, w2[(k+1)*64+lane], o);
            o = fmaf(v.z, w2[(k+2)*64+lane], o);
            o = fmaf(v.w, w2[(k+3)*64+lane], o);
        }
        ef[(size_t)e * 64 + lane] = __float2bfloat16(o);
    }
}

__global__ __launch_bounds__(256) void msg_agg_kernel(
    const int* __restrict__ src, const int* __restrict__ dst,
    const float* __restrict__ h, const __hip_bfloat16* __restrict__ ef,
    float* __restrict__ agg)
{
    int tid = blockIdx.x * 256 + threadIdx.x;
    int e = tid >> 4;
    if (e >= NE) return;
    int q = tid & 15;
    int s = src[e], d = dst[e];
    float4 hv = *(const float4*)(h + (size_t)s * 64 + q * 4);
    ushort4 ev = *(const ushort4*)(ef + (size_t)e * 64 + q * 4);
    float m0 = fmaxf(hv.x + __uint_as_float((unsigned)ev.x << 16), 0.f);
    float m1 = fmaxf(hv.y + __uint_as_float((unsigned)ev.y << 16), 0.f);
    float m2 = fmaxf(hv.z + __uint_as_float((unsigned)ev.z << 16), 0.f);
    float m3 = fmaxf(hv.w + __uint_as_float((unsigned)ev.w << 16), 0.f);
    float* ap = agg + (size_t)d * 64 + q * 4;
    atomicAdd(ap + 0, m0); atomicAdd(ap + 1, m1);
    atomicAdd(ap + 2, m2); atomicAdd(ap + 3, m3);
}

__global__ __launch_bounds__(256) void node_update_kernel(
    float* __restrict__ h, float* __restrict__ agg,
    const float* __restrict__ wa, const float* __restrict__ ba,
    const float* __restrict__ wb, const float* __restrict__ bb)
{
    __shared__ float s_wat[64 * 68], s_wbt[64 * 68];
    __shared__ float s_ba[64], s_bb[64];
    __shared__ float s_u[4][64], s_hid[4][64];
    int t = threadIdx.x;
    load_wT(wa, s_wat, t);
    load_wT(wb, s_wbt, t);
    if (t < 64) { s_ba[t] = ba[t]; s_bb[t] = bb[t]; }
    __syncthreads();
    int lane = t & 63, grp = t >> 6;
    const int groups = (NN + 3) >> 2;
    for (int g = blockIdx.x; g < groups; g += gridDim.x) {
        int n = (g << 2) + grp;
        if (n < NN) {
            size_t off = (size_t)n * 64 + lane;
            float uv = h[off] + agg[off];
            agg[off] = 0.f;
            s_u[grp][lane] = uv;
            float hid = silu_f(s_ba[lane] + dot64(s_u[grp], s_wat + lane * 68));
            s_hid[grp][lane] = hid;
            float o = silu_f(s_bb[lane] + dot64(s_hid[grp], s_wbt + lane * 68));
            h[off] = o;
        }
    }
}

__global__ __launch_bounds__(256) void final_kernel(
    const float* __restrict__ hin,
    const float* __restrict__ w1, const float* __restrict__ b1,
    const float* __restrict__ w2, const float* __restrict__ b2,
    float* __restrict__ out)
{
    __shared__ float s_w1t[64 * 68];
    __shared__ float s_b1[64], s_w2[64];
    __shared__ float s_u[4][64];
    int t = threadIdx.x;
    load_wT(w1, s_w1t, t);
    if (t < 64) { s_b1[t] = b1[t]; s_w2[t] = w2[t]; }
    __syncthreads();
    int lane = t & 63, grp = t >> 6;
    float b2v = b2[0];
    const int groups = (NN + 3) >> 2;
    for (int g = blockIdx.x; g < groups; g += gridDim.x) {
        int n = (g << 2) + grp;
        if (n < NN) {
            s_u[grp][lane] = hin[(size_t)n * 64 + lane];
            float hid = silu_f(s_b1[lane] + dot64(s_u[grp], s_w1t + lane * 68));
            float v = hid * s_w2[lane];
#pragma unroll
            for (int off = 32; off; off >>= 1) v += __shfl_xor(v, off, 64);
            if (lane == 0) out[n] = v + b2v;
        }
    }
}

extern "C" void kernel_launch(void* const* d_in, const int* in_sizes, int n_in,
                              void* d_out, int out_size, void* d_ws, size_t ws_size,
                              hipStream_t stream) {
    const float* cond = (const float*)d_in[0];
    const float* ea   = (const float*)d_in[1];
    const int*   ei   = (const int*)d_in[2];
    // d_in[3] = batch: unused (t = zeros -> t_feat rows identical)
    const float* w_n1 = (const float*)d_in[4];  const float* b_n1 = (const float*)d_in[5];
    const float* w_n2 = (const float*)d_in[6];  const float* b_n2 = (const float*)d_in[7];
    const float* w_e1 = (const float*)d_in[8];  const float* b_e1 = (const float*)d_in[9];
    const float* w_e2 = (const float*)d_in[10]; const float* b_e2 = (const float*)d_in[11];
    const float* w_t  = (const float*)d_in[12]; const float* b_t  = (const float*)d_in[13];
    const float* wca[3] = {(const float*)d_in[14], (const float*)d_in[18], (const float*)d_in[22]};
    const float* bca[3] = {(const float*)d_in[15], (const float*)d_in[19], (const float*)d_in[23]};
    const float* wcb[3] = {(const float*)d_in[16], (const float*)d_in[20], (const float*)d_in[24]};
    const float* bcb[3] = {(const float*)d_in[17], (const float*)d_in[21], (const float*)d_in[25]};
    const float* w_f1 = (const float*)d_in[26]; const float* b_f1 = (const float*)d_in[27];
    const float* w_f2 = (const float*)d_in[28]; const float* b_f2 = (const float*)d_in[29];
    float* out = (float*)d_out;

    const int* srcp = ei;
    const int* dstp = ei + NE;
    char* ws = (char*)d_ws;

    // fast-path layout (no ef buffer!): tvec | h | u | offs | cnt | bsum | bscan | rank | pack(+16 pad)
    // ~84 MB total. rank consumed by scatter; pack persists across all 3 layers.
    size_t o = 0;
    float* tvec = (float*)(ws + o); o += 256;
    float* h    = (float*)(ws + o); o += (size_t)NN * 64 * 4;
    float* u    = (float*)(ws + o); o += (size_t)NN * 64 * 4;
    int* offs   = (int*)(ws + o);   o += ((size_t)(NN + 1) * 4 + 255) & ~255ULL;
    int* cnt    = (int*)(ws + o);   o += ((size_t)NN * 4 + 255) & ~255ULL;
    int* bsum   = (int*)(ws + o);   o += 512;
    int* bscan  = (int*)(ws + o);   o += 512;
    int* rank   = (int*)(ws + o);   o += (size_t)NE * 4;
    intx4* pack = (intx4*)(ws + o); o += (size_t)(NE + 16) * 16;
    const size_t REQ_A = o;

    if (ws_size >= REQ_A) {
        // ---- fast path: CSR + fused MFMA-recompute aggregation (no ef materialization) ----
        hipLaunchKernelGGL(tvec_kernel, dim3(1), dim3(64), 0, stream, w_t, b_t, tvec);
        hipLaunchKernelGGL(zero_kernel, dim3((NN + 255) / 256), dim3(256), 0, stream, cnt, NN);
        hipLaunchKernelGGL(hist_rank_kernel, dim3((NE + 255) / 256), dim3(256), 0, stream,
                           dstp, cnt, rank);
        hipLaunchKernelGGL(scan1_kernel, dim3(SCAN_BLOCKS), dim3(256), 0, stream, cnt, offs, bsum);
        hipLaunchKernelGGL(scan2_kernel, dim3(1), dim3(128), 0, stream, bsum, bscan, SCAN_BLOCKS);
        hipLaunchKernelGGL(scan3_kernel, dim3((NN + 255) / 256), dim3(256), 0, stream, offs, bscan);
        hipLaunchKernelGGL(scatter_pack_kernel, dim3((NE + 255) / 256), dim3(256), 0, stream,
                           dstp, srcp, ea, offs, rank, pack);
        hipLaunchKernelGGL(pad_pack_kernel, dim3(1), dim3(16), 0, stream, pack);
        hipLaunchKernelGGL(node_init_kernel, dim3(1024), dim3(256), 0, stream,
                           cond, w_n1, b_n1, w_n2, b_n2, tvec, h, (float*)nullptr);
        for (int l = 0; l < 3; ++l) {
            hipLaunchKernelGGL(agg_fused_kernel, dim3((NN + 3) / 4), dim3(256), 0, stream,
                               h, u, offs, pack, w_e1, b_e1, w_e2, b_e2);
            hipLaunchKernelGGL(node_mlp_mfma_kernel, dim3(391), dim3(256), 0, stream,
                               u, h, wca[l], bca[l], wcb[l], bcb[l]);
        }
        hipLaunchKernelGGL(final_kernel, dim3(1024), dim3(256), 0, stream,
                           h, w_f1, b_f1, w_f2, b_f2, out);
    } else {
        // ---- fallback: proven round-2 path (256.0 MB) ----
        float* tvecB = (float*)ws;
        float* hB    = (float*)(ws + 256);
        float* agg   = hB + (size_t)NN * 64;
        __hip_bfloat16* efB = (__hip_bfloat16*)(agg + (size_t)NN * 64);
        hipLaunchKernelGGL(tvec_kernel, dim3(1), dim3(64), 0, stream, w_t, b_t, tvecB);
        hipLaunchKernelGGL(node_init_kernel, dim3(1024), dim3(256), 0, stream,
                           cond, w_n1, b_n1, w_n2, b_n2, tvecB, hB, agg);
        hipLaunchKernelGGL(edge_feat_fallback_kernel, dim3(1024), dim3(256), 0, stream,
                           ea, w_e1, b_e1, w_e2, b_e2, efB);
        for (int l = 0; l < 3; ++l) {
            hipLaunchKernelGGL(msg_agg_kernel, dim3((NE * 16) / 256), dim3(256), 0, stream,
                               srcp, dstp, hB, efB, agg);
            hipLaunchKernelGGL(node_update_kernel, dim3(1024), dim3(256), 0, stream,
                               hB, agg, wca[l], bca[l], wcb[l], bcb[l]);
        }
        hipLaunchKernelGGL(final_kernel, dim3(1024), dim3(256), 0, stream,
                           hB, w_f1, b_f1, w_f2, b_f2, out);
    }
}

// Round 12
// 577.371 us; speedup vs baseline: 1.5547x; 1.5547x over previous
//
#include <hip/hip_runtime.h>
#include <hip/hip_bf16.h>

#define NN 100000
#define NE 1600000
#define SCAN_BLOCKS 98   // ceil(100000/1024)

typedef short short8 __attribute__((ext_vector_type(8)));
typedef float floatx4 __attribute__((ext_vector_type(4)));
typedef int   intx4   __attribute__((ext_vector_type(4)));
typedef unsigned int uintx4 __attribute__((ext_vector_type(4)));
typedef unsigned short ushortx4 __attribute__((ext_vector_type(4)));

__device__ __forceinline__ float silu_f(float x){ return x / (1.0f + __expf(-x)); }

__device__ __forceinline__ unsigned short f2bf(float x) {
    __hip_bfloat16 h = __float2bfloat16(x);   // hardware RNE cvt
    unsigned short u; __builtin_memcpy(&u, &h, 2); return u;
}
__device__ __forceinline__ float bf2f(unsigned short u) {
    return __uint_as_float((unsigned)u << 16);
}
__device__ __forceinline__ float bflo(unsigned int v) { return __uint_as_float(v << 16); }
__device__ __forceinline__ float bfhi(unsigned int v) { return __uint_as_float(v & 0xffff0000u); }

// ---------- LDS dot (round-2..5 proven: measured SQ_LDS_BANK_CONFLICT == 0) ----------
__device__ __forceinline__ float dot64(const float* vec, const float* wrow) {
    float ax = 0.f, ay = 0.f, az = 0.f, aw = 0.f;
#pragma unroll
    for (int k = 0; k < 64; k += 4) {
        float4 w = *(const float4*)(wrow + k);
        float4 v = *(const float4*)(vec + k);
        ax = fmaf(v.x, w.x, ax); ay = fmaf(v.y, w.y, ay);
        az = fmaf(v.z, w.z, az); aw = fmaf(v.w, w.w, aw);
    }
    return (ax + ay) + (az + aw);
}
__device__ __forceinline__ void load_wT(const float* __restrict__ w, float* s, int t) {
    for (int i = t; i < 4096; i += 256) { int k = i >> 6, j = i & 63; s[j * 68 + k] = w[i]; }
}

// tvec[j] = b_t[j] + silu(1) * sum_{i=16..31} w_t[i][j]
__global__ void tvec_kernel(const float* __restrict__ w_t, const float* __restrict__ b_t,
                            float* __restrict__ tvec) {
    int j = threadIdx.x;
    const float s1 = 0.7310585786300049f;
    float acc = b_t[j];
#pragma unroll
    for (int i = 16; i < 32; ++i) acc = fmaf(s1, w_t[i * 64 + j], acc);
    tvec[j] = acc;
}

__global__ __launch_bounds__(256) void node_init_kernel(
    const float* __restrict__ cond,
    const float* __restrict__ w1, const float* __restrict__ b1,
    const float* __restrict__ w2, const float* __restrict__ b2,
    const float* __restrict__ tvec,
    float* __restrict__ h, float* __restrict__ agg)   // agg==nullptr on fast path
{
    __shared__ float s_w1[6 * 64];
    __shared__ float s_w2t[64 * 68];
    __shared__ float s_b1[64], s_b2[64];
    __shared__ float s_hid[4][64];
    int t = threadIdx.x;
    for (int i = t; i < 384; i += 256) s_w1[i] = w1[64 + i]; // rows 1..6 (row 0 hits zero column)
    load_wT(w2, s_w2t, t);
    if (t < 64) { s_b1[t] = b1[t]; s_b2[t] = b2[t] + tvec[t]; }
    __syncthreads();
    int lane = t & 63, grp = t >> 6;
    const int groups = (NN + 3) >> 2;
    for (int g = blockIdx.x; g < groups; g += gridDim.x) {
        int n = (g << 2) + grp;
        if (n < NN) {
            float acc = s_b1[lane];
#pragma unroll
            for (int i = 0; i < 6; ++i) acc = fmaf(cond[n * 6 + i], s_w1[i * 64 + lane], acc);
            s_hid[grp][lane] = silu_f(acc);
            float o = s_b2[lane] + dot64(s_hid[grp], s_w2t + lane * 68);
            size_t off = (size_t)n * 64 + lane;
            h[off] = o;
            if (agg) agg[off] = 0.f;
        }
    }
}

// ---------- CSR build ----------
__global__ __launch_bounds__(256) void zero_kernel(int* __restrict__ p, int n) {
    int i = blockIdx.x * 256 + threadIdx.x;
    if (i < n) p[i] = 0;
}
// histogram AND per-edge rank (rank = old count at dst)
__global__ __launch_bounds__(256) void hist_rank_kernel(const int* __restrict__ dst,
                                                        int* __restrict__ cnt,
                                                        int* __restrict__ rank) {
    int e = blockIdx.x * 256 + threadIdx.x;
    if (e < NE) rank[e] = atomicAdd(&cnt[dst[e]], 1);
}
__global__ __launch_bounds__(256) void scan1_kernel(const int* __restrict__ cnt,
                                                    int* __restrict__ offs, int* __restrict__ bsum) {
    __shared__ int s_w[4];
    int t = threadIdx.x;
    int base = blockIdx.x * 1024 + t * 4;
    int v0 = (base + 0 < NN) ? cnt[base + 0] : 0;
    int v1 = (base + 1 < NN) ? cnt[base + 1] : 0;
    int v2 = (base + 2 < NN) ? cnt[base + 2] : 0;
    int v3 = (base + 3 < NN) ? cnt[base + 3] : 0;
    int tsum = v0 + v1 + v2 + v3;
    int lane = t & 63, w = t >> 6;
    int x = tsum;
#pragma unroll
    for (int d = 1; d < 64; d <<= 1) { int y = __shfl_up(x, d, 64); if (lane >= d) x += y; }
    if (lane == 63) s_w[w] = x;
    __syncthreads();
    if (t == 0) {
        int a = 0;
#pragma unroll
        for (int i = 0; i < 4; ++i) { int b = s_w[i]; s_w[i] = a; a += b; }
        bsum[blockIdx.x] = a;
    }
    __syncthreads();
    int excl = x - tsum + s_w[w];
    if (base + 0 < NN) offs[base + 0] = excl;
    if (base + 1 < NN) offs[base + 1] = excl + v0;
    if (base + 2 < NN) offs[base + 2] = excl + v0 + v1;
    if (base + 3 < NN) offs[base + 3] = excl + v0 + v1 + v2;
}
__global__ void scan2_kernel(const int* __restrict__ bsum, int* __restrict__ bscan, int nb) {
    __shared__ int s_w[2];
    int t = threadIdx.x;
    int v = (t < nb) ? bsum[t] : 0;
    int lane = t & 63, w = t >> 6;
    int x = v;
#pragma unroll
    for (int d = 1; d < 64; d <<= 1) { int y = __shfl_up(x, d, 64); if (lane >= d) x += y; }
    if (lane == 63) s_w[w] = x;
    __syncthreads();
    int add = (w == 1) ? s_w[0] : 0;
    if (t < nb) bscan[t] = x - v + add;
}
__global__ __launch_bounds__(256) void scan3_kernel(int* __restrict__ offs,
                                                    const int* __restrict__ bscan) {
    int i = blockIdx.x * 256 + threadIdx.x;
    if (i < NN) offs[i] = offs[i] + bscan[i >> 10];
    if (i == 0) offs[NN] = NE;
}
// atomic-free scatter: pos = offs[dst] + rank  (offs is read-only, L2-replicated)
__global__ __launch_bounds__(256) void scatter_pack_kernel(const int* __restrict__ dst,
                                                           const int* __restrict__ src,
                                                           const float* __restrict__ ea,
                                                           const int* __restrict__ offs,
                                                           const int* __restrict__ rank,
                                                           intx4* __restrict__ pack) {
    int e = blockIdx.x * 256 + threadIdx.x;
    if (e >= NE) return;
    float2 a = *(const float2*)(ea + (size_t)e * 2);
    int pos = offs[dst[e]] + rank[e];
    intx4 p = { src[e], __float_as_int(a.x), __float_as_int(a.y), 0 };
    pack[pos] = p;
}
// dense src stream for agg (linear, cheap); overwrites the rank buffer (already consumed)
__global__ __launch_bounds__(256) void copy_src_kernel(const intx4* __restrict__ pack,
                                                       int* __restrict__ srcc) {
    int i = blockIdx.x * 256 + threadIdx.x;
    if (i < NE) srcc[i] = pack[i].x;
}

// ---------- edge MLP via MFMA, linear pack input, nt vector stores (round-9 proven) ----------
__global__ __launch_bounds__(256, 2) void edge_feat_mfma_kernel(
    const intx4* __restrict__ pack,
    const float* __restrict__ w1, const float* __restrict__ b1,
    const float* __restrict__ w2, const float* __restrict__ b2,
    __hip_bfloat16* __restrict__ ef)
{
    int t = threadIdx.x;
    int lane = t & 63, wv = t >> 6;
    int er = lane & 15;        // A row / C logical col
    int kg = lane >> 4;        // k-group 0..3
    float w1x[2][8], w1y[2][8], b1v[2][8];
#pragma unroll
    for (int c = 0; c < 2; ++c)
#pragma unroll
        for (int j = 0; j < 8; ++j) {
            int k = c * 32 + kg * 8 + j;
            w1x[c][j] = w1[k];
            w1y[c][j] = w1[64 + k];
            b1v[c][j] = b1[k];
        }
    short8 bfrag[2][4];
#pragma unroll
    for (int c = 0; c < 2; ++c)
#pragma unroll
        for (int tt = 0; tt < 4; ++tt)
#pragma unroll
            for (int j = 0; j < 8; ++j) {
                int k = c * 32 + kg * 8 + j;
                bfrag[c][tt][j] = (short)f2bf(w2[k * 64 + 4 * er + tt]);
            }
    float4 b2v = *(const float4*)(b2 + 4 * er);

    const int nchunk = NE / 16;
    for (int ch = blockIdx.x * 4 + wv; ch < nchunk; ch += gridDim.x * 4) {
        int i0 = ch * 16;
        intx4 p = __builtin_nontemporal_load(pack + i0 + er);   // coalesced 16B stream
        float ax = __int_as_float(p.y), ay = __int_as_float(p.z);
        short8 afrag[2];
#pragma unroll
        for (int c = 0; c < 2; ++c)
#pragma unroll
            for (int j = 0; j < 8; ++j) {
                float hid = silu_f(fmaf(ax, w1x[c][j], fmaf(ay, w1y[c][j], b1v[c][j])));
                afrag[c][j] = (short)f2bf(hid);
            }
        floatx4 acc0 = {0,0,0,0}, acc1 = {0,0,0,0}, acc2 = {0,0,0,0}, acc3 = {0,0,0,0};
        acc0 = __builtin_amdgcn_mfma_f32_16x16x32_bf16(afrag[0], bfrag[0][0], acc0, 0, 0, 0);
        acc0 = __builtin_amdgcn_mfma_f32_16x16x32_bf16(afrag[1], bfrag[1][0], acc0, 0, 0, 0);
        acc1 = __builtin_amdgcn_mfma_f32_16x16x32_bf16(afrag[0], bfrag[0][1], acc1, 0, 0, 0);
        acc1 = __builtin_amdgcn_mfma_f32_16x16x32_bf16(afrag[1], bfrag[1][1], acc1, 0, 0, 0);
        acc2 = __builtin_amdgcn_mfma_f32_16x16x32_bf16(afrag[0], bfrag[0][2], acc2, 0, 0, 0);
        acc2 = __builtin_amdgcn_mfma_f32_16x16x32_bf16(afrag[1], bfrag[1][2], acc2, 0, 0, 0);
        acc3 = __builtin_amdgcn_mfma_f32_16x16x32_bf16(afrag[0], bfrag[0][3], acc3, 0, 0, 0);
        acc3 = __builtin_amdgcn_mfma_f32_16x16x32_bf16(afrag[1], bfrag[1][3], acc3, 0, 0, 0);
#pragma unroll
        for (int q = 0; q < 4; ++q) {
            ushortx4 o;
            o.x = f2bf(acc0[q] + b2v.x);
            o.y = f2bf(acc1[q] + b2v.y);
            o.z = f2bf(acc2[q] + b2v.z);
            o.w = f2bf(acc3[q] + b2v.w);
            __builtin_nontemporal_store(o,
                (ushortx4*)((unsigned short*)ef + (size_t)(i0 + kg * 4 + q) * 64 + 4 * er));
        }
    }
}

// ---------- aggregation v3: 2 nodes/wave, 4 edge-rows per step, 16B loads everywhere ----------
// Half-wave lane layout: c = l32&7 covers cols [8c,8c+8); rs = l32>>3 is the row slot.
// Per step: 1x uintx4 ef load + 2x float4 h gather per lane -> 4 rows processed.
__global__ __launch_bounds__(256) void agg_kernel(
    const float* __restrict__ hin, float* __restrict__ u,
    const int* __restrict__ offs, const int* __restrict__ srcc,
    const __hip_bfloat16* __restrict__ ef)
{
    int t = threadIdx.x;
    int lane = t & 63, wv = t >> 6;
    int half = lane >> 5, l32 = lane & 31;
    int c = l32 & 7, rs = l32 >> 3;
    int n = blockIdx.x * 8 + wv * 2 + half;
    if (n >= NN) return;
    const unsigned int* efu = (const unsigned int*)ef;
    int i0 = offs[n], i1 = offs[n + 1];
    float a0 = 0.f, a1 = 0.f, a2 = 0.f, a3 = 0.f, a4 = 0.f, a5 = 0.f, a6 = 0.f, a7 = 0.f;
    for (int ib = i0; ib < i1; ib += 32) {
        int m = i1 - ib; if (m > 32) m = 32;
        int myS = 0;
        if (l32 < m) myS = __builtin_nontemporal_load(srcc + ib + l32);
        for (int rb = 0; rb < m; rb += 4) {
            int r = rb + rs;
            int s = __shfl(myS, r, 32);
            bool valid = r < m;
            if (!valid) s = 0;                 // safe address; masked out of acc
            uintx4 ev = __builtin_nontemporal_load(
                (const uintx4*)(efu + (size_t)(ib + r) * 32 + c * 4));
            float4 h0 = *(const float4*)(hin + (size_t)s * 64 + c * 8);
            float4 h1 = *(const float4*)(hin + (size_t)s * 64 + c * 8 + 4);
            if (valid) {
                a0 += fmaxf(h0.x + bflo(ev.x), 0.f);
                a1 += fmaxf(h0.y + bfhi(ev.x), 0.f);
                a2 += fmaxf(h0.z + bflo(ev.y), 0.f);
                a3 += fmaxf(h0.w + bfhi(ev.y), 0.f);
                a4 += fmaxf(h1.x + bflo(ev.z), 0.f);
                a5 += fmaxf(h1.y + bfhi(ev.z), 0.f);
                a6 += fmaxf(h1.z + bflo(ev.w), 0.f);
                a7 += fmaxf(h1.w + bfhi(ev.w), 0.f);
            }
        }
    }
    // reduce across the 4 row slots (lanes l32^8, l32^16 share c)
#pragma unroll
    for (int d = 8; d <= 16; d <<= 1) {
        a0 += __shfl_xor(a0, d, 32); a1 += __shfl_xor(a1, d, 32);
        a2 += __shfl_xor(a2, d, 32); a3 += __shfl_xor(a3, d, 32);
        a4 += __shfl_xor(a4, d, 32); a5 += __shfl_xor(a5, d, 32);
        a6 += __shfl_xor(a6, d, 32); a7 += __shfl_xor(a7, d, 32);
    }
    if (rs == 0) {
        float4 s0 = *(const float4*)(hin + (size_t)n * 64 + c * 8);
        float4 s1 = *(const float4*)(hin + (size_t)n * 64 + c * 8 + 4);
        float4 o0, o1;
        o0.x = s0.x + a0; o0.y = s0.y + a1; o0.z = s0.z + a2; o0.w = s0.w + a3;
        o1.x = s1.x + a4; o1.y = s1.y + a5; o1.z = s1.z + a6; o1.w = s1.w + a7;
        *(float4*)(u + (size_t)n * 64 + c * 8) = o0;
        *(float4*)(u + (size_t)n * 64 + c * 8 + 4) = o1;
    }
}

// ---------- node MLP via MFMA, 3-term bf16 split (~fp32 precision), weights in B-frags ----------
__global__ __launch_bounds__(256) void node_mlp_mfma_kernel(
    const float* __restrict__ u, float* __restrict__ h,
    const float* __restrict__ wa, const float* __restrict__ ba,
    const float* __restrict__ wb, const float* __restrict__ bb)
{
    __shared__ float s_hid[4][16 * 72];
    int t = threadIdx.x, lane = t & 63, wv = t >> 6;
    int er = lane & 15, kg = lane >> 4;
    short8 waH[2][4], waL[2][4], wbH[2][4], wbL[2][4];
#pragma unroll
    for (int c = 0; c < 2; ++c)
#pragma unroll
        for (int tt = 0; tt < 4; ++tt)
#pragma unroll
            for (int j = 0; j < 8; ++j) {
                int k = c * 32 + kg * 8 + j;
                float vA = wa[k * 64 + 4 * er + tt];
                unsigned short hA = f2bf(vA);
                waH[c][tt][j] = (short)hA;
                waL[c][tt][j] = (short)f2bf(vA - bf2f(hA));
                float vB = wb[k * 64 + 4 * er + tt];
                unsigned short hB = f2bf(vB);
                wbH[c][tt][j] = (short)hB;
                wbL[c][tt][j] = (short)f2bf(vB - bf2f(hB));
            }
    float4 bav = *(const float4*)(ba + 4 * er);
    float4 bbv = *(const float4*)(bb + 4 * er);
    float* hid = s_hid[wv];

    const int ntile = NN / 16;  // 6250
    for (int tile = blockIdx.x * 4 + wv; tile < ntile; tile += gridDim.x * 4) {
        int i0 = tile * 16;
        short8 aH[2], aL[2];
#pragma unroll
        for (int c = 0; c < 2; ++c) {
            const float* up = u + (size_t)(i0 + er) * 64 + c * 32 + kg * 8;
            float4 u0 = *(const float4*)(up);
            float4 u1 = *(const float4*)(up + 4);
            float uv[8] = {u0.x, u0.y, u0.z, u0.w, u1.x, u1.y, u1.z, u1.w};
#pragma unroll
            for (int j = 0; j < 8; ++j) {
                unsigned short hi = f2bf(uv[j]);
                aH[c][j] = (short)hi;
                aL[c][j] = (short)f2bf(uv[j] - bf2f(hi));
            }
        }
        floatx4 acc[4] = {{0,0,0,0},{0,0,0,0},{0,0,0,0},{0,0,0,0}};
#pragma unroll
        for (int tt = 0; tt < 4; ++tt)
#pragma unroll
            for (int c = 0; c < 2; ++c) {
                acc[tt] = __builtin_amdgcn_mfma_f32_16x16x32_bf16(aH[c], waH[c][tt], acc[tt], 0, 0, 0);
                acc[tt] = __builtin_amdgcn_mfma_f32_16x16x32_bf16(aL[c], waH[c][tt], acc[tt], 0, 0, 0);
                acc[tt] = __builtin_amdgcn_mfma_f32_16x16x32_bf16(aH[c], waL[c][tt], acc[tt], 0, 0, 0);
            }
#pragma unroll
        for (int q = 0; q < 4; ++q) {
            float4 hv;
            hv.x = silu_f(acc[0][q] + bav.x);
            hv.y = silu_f(acc[1][q] + bav.y);
            hv.z = silu_f(acc[2][q] + bav.z);
            hv.w = silu_f(acc[3][q] + bav.w);
            *(float4*)(hid + (kg * 4 + q) * 72 + 4 * er) = hv;
        }
        short8 cH[2], cL[2];
#pragma unroll
        for (int c = 0; c < 2; ++c) {
            const float* hp = hid + er * 72 + c * 32 + kg * 8;
            float4 h0 = *(const float4*)(hp);
            float4 h1 = *(const float4*)(hp + 4);
            float hv[8] = {h0.x, h0.y, h0.z, h0.w, h1.x, h1.y, h1.z, h1.w};
#pragma unroll
            for (int j = 0; j < 8; ++j) {
                unsigned short hi = f2bf(hv[j]);
                cH[c][j] = (short)hi;
                cL[c][j] = (short)f2bf(hv[j] - bf2f(hi));
            }
        }
        floatx4 acc2[4] = {{0,0,0,0},{0,0,0,0},{0,0,0,0},{0,0,0,0}};
#pragma unroll
        for (int tt = 0; tt < 4; ++tt)
#pragma unroll
            for (int c = 0; c < 2; ++c) {
                acc2[tt] = __builtin_amdgcn_mfma_f32_16x16x32_bf16(cH[c], wbH[c][tt], acc2[tt], 0, 0, 0);
                acc2[tt] = __builtin_amdgcn_mfma_f32_16x16x32_bf16(cL[c], wbH[c][tt], acc2[tt], 0, 0, 0);
                acc2[tt] = __builtin_amdgcn_mfma_f32_16x16x32_bf16(cH[c], wbL[c][tt], acc2[tt], 0, 0, 0);
            }
#pragma unroll
        for (int q = 0; q < 4; ++q) {
            float4 ov;
            ov.x = silu_f(acc2[0][q] + bbv.x);
            ov.y = silu_f(acc2[1][q] + bbv.y);
            ov.z = silu_f(acc2[2][q] + bbv.z);
            ov.w = silu_f(acc2[3][q] + bbv.w);
            *(float4*)(h + (size_t)(i0 + kg * 4 + q) * 64 + 4 * er) = ov;
        }
    }
}

// ---------- fallback path (round-2 proven) ----------
__global__ __launch_bounds__(256, 3) void edge_feat_fallback_kernel(
    const float* __restrict__ ea,
    const float* __restrict__ w1, const float* __restrict__ b1,
    const float* __restrict__ w2, const float* __restrict__ b2,
    __hip_bfloat16* __restrict__ ef)
{
    __shared__ float s_w1[128], s_b1[64], s_b2[64];
    __shared__ float s_hid[4][64];
    int t = threadIdx.x;
    if (t < 128) s_w1[t] = w1[t];
    if (t < 64) { s_b1[t] = b1[t]; s_b2[t] = b2[t]; }
    int lane = t & 63, grp = t >> 6;
    __syncthreads();
    const int groups = NE >> 2;
    for (int g = blockIdx.x; g < groups; g += gridDim.x) {
        int e = (g << 2) + grp;
        float2 a = *(const float2*)(ea + (size_t)e * 2);
        float acc = fmaf(a.x, s_w1[lane], fmaf(a.y, s_w1[64 + lane], s_b1[lane]));
        s_hid[grp][lane] = silu_f(acc);
        float o = s_b2[lane];
#pragma unroll
        for (int k = 0; k < 64; k += 4) {
            float4 v = *(const float4*)&s_hid[grp][k];
            o = fmaf(v.x, w2[(k+0)*64+lane], o);
            o = fmaf(v.y, w2[(k+1)*64+lane], o);
            o = fmaf(v.z, w2[(k+2)*64+lane], o);
            o = fmaf(v.w, w2[(k+3)*64+lane], o);
        }
        ef[(size_t)e * 64 + lane] = __float2bfloat16(o);
    }
}

__global__ __launch_bounds__(256) void msg_agg_kernel(
    const int* __restrict__ src, const int* __restrict__ dst,
    const float* __restrict__ h, const __hip_bfloat16* __restrict__ ef,
    float* __restrict__ agg)
{
    int tid = blockIdx.x * 256 + threadIdx.x;
    int e = tid >> 4;
    if (e >= NE) return;
    int q = tid & 15;
    int s = src[e], d = dst[e];
    float4 hv = *(const float4*)(h + (size_t)s * 64 + q * 4);
    ushort4 ev = *(const ushort4*)(ef + (size_t)e * 64 + q * 4);
    float m0 = fmaxf(hv.x + __uint_as_float((unsigned)ev.x << 16), 0.f);
    float m1 = fmaxf(hv.y + __uint_as_float((unsigned)ev.y << 16), 0.f);
    float m2 = fmaxf(hv.z + __uint_as_float((unsigned)ev.z << 16), 0.f);
    float m3 = fmaxf(hv.w + __uint_as_float((unsigned)ev.w << 16), 0.f);
    float* ap = agg + (size_t)d * 64 + q * 4;
    atomicAdd(ap + 0, m0); atomicAdd(ap + 1, m1);
    atomicAdd(ap + 2, m2); atomicAdd(ap + 3, m3);
}

__global__ __launch_bounds__(256) void node_update_kernel(
    float* __restrict__ h, float* __restrict__ agg,
    const float* __restrict__ wa, const float* __restrict__ ba,
    const float* __restrict__ wb, const float* __restrict__ bb)
{
    __shared__ float s_wat[64 * 68], s_wbt[64 * 68];
    __shared__ float s_ba[64], s_bb[64];
    __shared__ float s_u[4][64], s_hid[4][64];
    int t = threadIdx.x;
    load_wT(wa, s_wat, t);
    load_wT(wb, s_wbt, t);
    if (t < 64) { s_ba[t] = ba[t]; s_bb[t] = bb[t]; }
    __syncthreads();
    int lane = t & 63, grp = t >> 6;
    const int groups = (NN + 3) >> 2;
    for (int g = blockIdx.x; g < groups; g += gridDim.x) {
        int n = (g << 2) + grp;
        if (n < NN) {
            size_t off = (size_t)n * 64 + lane;
            float uv = h[off] + agg[off];
            agg[off] = 0.f;
            s_u[grp][lane] = uv;
            float hid = silu_f(s_ba[lane] + dot64(s_u[grp], s_wat + lane * 68));
            s_hid[grp][lane] = hid;
            float o = silu_f(s_bb[lane] + dot64(s_hid[grp], s_wbt + lane * 68));
            h[off] = o;
        }
    }
}

__global__ __launch_bounds__(256) void final_kernel(
    const float* __restrict__ hin,
    const float* __restrict__ w1, const float* __restrict__ b1,
    const float* __restrict__ w2, const float* __restrict__ b2,
    float* __restrict__ out)
{
    __shared__ float s_w1t[64 * 68];
    __shared__ float s_b1[64], s_w2[64];
    __shared__ float s_u[4][64];
    int t = threadIdx.x;
    load_wT(w1, s_w1t, t);
    if (t < 64) { s_b1[t] = b1[t]; s_w2[t] = w2[t]; }
    __syncthreads();
    int lane = t & 63, grp = t >> 6;
    float b2v = b2[0];
    const int groups = (NN + 3) >> 2;
    for (int g = blockIdx.x; g < groups; g += gridDim.x) {
        int n = (g << 2) + grp;
        if (n < NN) {
            s_u[grp][lane] = hin[(size_t)n * 64 + lane];
            float hid = silu_f(s_b1[lane] + dot64(s_u[grp], s_w1t + lane * 68));
            float v = hid * s_w2[lane];
#pragma unroll
            for (int off = 32; off; off >>= 1) v += __shfl_xor(v, off, 64);
            if (lane == 0) out[n] = v + b2v;
        }
    }
}

extern "C" void kernel_launch(void* const* d_in, const int* in_sizes, int n_in,
                              void* d_out, int out_size, void* d_ws, size_t ws_size,
                              hipStream_t stream) {
    const float* cond = (const float*)d_in[0];
    const float* ea   = (const float*)d_in[1];
    const int*   ei   = (const int*)d_in[2];
    // d_in[3] = batch: unused (t = zeros -> t_feat rows identical)
    const float* w_n1 = (const float*)d_in[4];  const float* b_n1 = (const float*)d_in[5];
    const float* w_n2 = (const float*)d_in[6];  const float* b_n2 = (const float*)d_in[7];
    const float* w_e1 = (const float*)d_in[8];  const float* b_e1 = (const float*)d_in[9];
    const float* w_e2 = (const float*)d_in[10]; const float* b_e2 = (const float*)d_in[11];
    const float* w_t  = (const float*)d_in[12]; const float* b_t  = (const float*)d_in[13];
    const float* wca[3] = {(const float*)d_in[14], (const float*)d_in[18], (const float*)d_in[22]};
    const float* bca[3] = {(const float*)d_in[15], (const float*)d_in[19], (const float*)d_in[23]};
    const float* wcb[3] = {(const float*)d_in[16], (const float*)d_in[20], (const float*)d_in[24]};
    const float* bcb[3] = {(const float*)d_in[17], (const float*)d_in[21], (const float*)d_in[25]};
    const float* w_f1 = (const float*)d_in[26]; const float* b_f1 = (const float*)d_in[27];
    const float* w_f2 = (const float*)d_in[28]; const float* b_f2 = (const float*)d_in[29];
    float* out = (float*)d_out;

    const int* srcp = ei;
    const int* dstp = ei + NE;
    char* ws = (char*)d_ws;

    // fast-path layout: tvec | h | u | offs | cnt | bsum | bscan | srcc | ef(+4 rows pad)
    // pack(intx4, NE*16 = 25.6 MB) ALIASES u (consumed before agg writes u).
    // rank(int, NE) ALIASES srcc (consumed by scatter before copy_src overwrites).
    size_t o = 0;
    float* tvec = (float*)(ws + o); o += 256;
    float* h    = (float*)(ws + o); o += (size_t)NN * 64 * 4;
    float* u    = (float*)(ws + o); o += (size_t)NN * 64 * 4;
    int* offs   = (int*)(ws + o);   o += ((size_t)(NN + 1) * 4 + 255) & ~255ULL;
    int* cnt    = (int*)(ws + o);   o += ((size_t)NN * 4 + 255) & ~255ULL;
    int* bsum   = (int*)(ws + o);   o += 512;
    int* bscan  = (int*)(ws + o);   o += 512;
    int* srcc   = (int*)(ws + o);   o += (size_t)NE * 4;
    __hip_bfloat16* ef = (__hip_bfloat16*)(ws + o); o += (size_t)(NE + 4) * 64 * 2;
    const size_t REQ_A = o;
    intx4* pack = (intx4*)u;   // alias: NE*16 = 25.6 MB == sizeof(u)
    int* rank = srcc;          // alias: consumed by scatter, then overwritten by copy_src

    if (ws_size >= REQ_A) {
        // ---- fast path: CSR (rank-based atomic-free scatter) + MFMA MLPs + v3 gather agg ----
        hipLaunchKernelGGL(tvec_kernel, dim3(1), dim3(64), 0, stream, w_t, b_t, tvec);
        hipLaunchKernelGGL(zero_kernel, dim3((NN + 255) / 256), dim3(256), 0, stream, cnt, NN);
        hipLaunchKernelGGL(hist_rank_kernel, dim3((NE + 255) / 256), dim3(256), 0, stream,
                           dstp, cnt, rank);
        hipLaunchKernelGGL(scan1_kernel, dim3(SCAN_BLOCKS), dim3(256), 0, stream, cnt, offs, bsum);
        hipLaunchKernelGGL(scan2_kernel, dim3(1), dim3(128), 0, stream, bsum, bscan, SCAN_BLOCKS);
        hipLaunchKernelGGL(scan3_kernel, dim3((NN + 255) / 256), dim3(256), 0, stream, offs, bscan);
        hipLaunchKernelGGL(scatter_pack_kernel, dim3((NE + 255) / 256), dim3(256), 0, stream,
                           dstp, srcp, ea, offs, rank, pack);
        hipLaunchKernelGGL(copy_src_kernel, dim3((NE + 255) / 256), dim3(256), 0, stream,
                           pack, srcc);
        hipLaunchKernelGGL(node_init_kernel, dim3(1024), dim3(256), 0, stream,
                           cond, w_n1, b_n1, w_n2, b_n2, tvec, h, (float*)nullptr);
        hipLaunchKernelGGL(edge_feat_mfma_kernel, dim3(2048), dim3(256), 0, stream,
                           pack, w_e1, b_e1, w_e2, b_e2, ef);   // ef in CSR order
        for (int l = 0; l < 3; ++l) {
            hipLaunchKernelGGL(agg_kernel, dim3((NN + 7) / 8), dim3(256), 0, stream,
                               h, u, offs, srcc, ef);
            hipLaunchKernelGGL(node_mlp_mfma_kernel, dim3(391), dim3(256), 0, stream,
                               u, h, wca[l], bca[l], wcb[l], bcb[l]);
        }
        hipLaunchKernelGGL(final_kernel, dim3(1024), dim3(256), 0, stream,
                           h, w_f1, b_f1, w_f2, b_f2, out);
    } else {
        // ---- fallback: proven round-2 path (256.0 MB) ----
        float* tvecB = (float*)ws;
        float* hB    = (float*)(ws + 256);
        float* agg   = hB + (size_t)NN * 64;
        __hip_bfloat16* efB = (__hip_bfloat16*)(agg + (size_t)NN * 64);
        hipLaunchKernelGGL(tvec_kernel, dim3(1), dim3(64), 0, stream, w_t, b_t, tvecB);
        hipLaunchKernelGGL(node_init_kernel, dim3(1024), dim3(256), 0, stream,
                           cond, w_n1, b_n1, w_n2, b_n2, tvecB, hB, agg);
        hipLaunchKernelGGL(edge_feat_fallback_kernel, dim3(1024), dim3(256), 0, stream,
                           ea, w_e1, b_e1, w_e2, b_e2, efB);
        for (int l = 0; l < 3; ++l) {
            hipLaunchKernelGGL(msg_agg_kernel, dim3((NE * 16) / 256), dim3(256), 0, stream,
                               srcp, dstp, hB, efB, agg);
            hipLaunchKernelGGL(node_update_kernel, dim3(1024), dim3(256), 0, stream,
                               hB, agg, wca[l], bca[l], wcb[l], bcb[l]);
        }
        hipLaunchKernelGGL(final_kernel, dim3(1024), dim3(256), 0, stream,
                           hB, w_f1, b_f1, w_f2, b_f2, out);
    }
}